// Round 15
// baseline (457.780 us; speedup 1.0000x reference)
//
#include <hip/hip_runtime.h>
#include <hip/hip_bf16.h>
#include <math.h>

#define D 2048
#define H 256
#define E 16
#define TMB 32                 // tokens per block
#define BK 32                  // k-chunk; two 16-k half passes
#define NCH (D / BK)           // 64
#define LDW 36                 // LDS row stride: in-phase banks 4*(tx%8) -> 2-way free
#define WP_OFF 0               // [256][36] = 9216
#define X_OFF  9216            // [32][36]  = 1152 -> staging ends 10368
#define SB_LDW 257
#define SB_OFF 0               // [32][257] = 8224 (aliases staging during post)
#define WG_OFF 8224            // [16][256] = 4096 -> 12320
#define LB_OFF 12320
#define Z_OFF  12336
#define SMEM_FLOATS 12352      // 49.4 KB
#define THREADS 512
#define WS_STRIDE 20

// HARD-WON (R5,R8-R12,R14): bare __launch_bounds__(N) ONLY. Any occupancy hint
// (2nd arg / waves_per_eu) => 64-VGPR cap or LDS padding => spill/residency loss.
__global__ __launch_bounds__(THREADS)
void router_main(const float* __restrict__ x, const float* __restrict__ Wp,
                 const float* __restrict__ Wg, const float* __restrict__ lnw_g,
                 const float* __restrict__ lnb_g, const float* __restrict__ temp_g,
                 float* __restrict__ out_rw, float* __restrict__ out_disp,
                 float* __restrict__ ws_part)
{
    __shared__ __align__(16) float smem[SMEM_FLOATS];
    const int t  = threadIdx.x;
    const int tx = t & 15;           // h-lane (lane bits 0-3)
    const int ku = (t >> 4) & 3;     // 4-k window within each 16-k half (lane bits 4-5)
    const int tb = (t >> 6) & 3;     // token octet (wave bits)
    const int hb = t >> 8;           // h-half (wave bit)
    const int tok0 = blockIdx.x * TMB;

    float acc[8][8];
    #pragma unroll
    for (int i = 0; i < 8; ++i)
        #pragma unroll
        for (int j = 0; j < 8; ++j) acc[i][j] = 0.f;

    // staging: Wp tile 256x32 = 2048 f4 (4/thread, coalesced); x 32x32 = 256 f4 (t<256)
    float4 wst[4], xst;
    auto ISSUE = [&](int k0) {
        #pragma unroll
        for (int p = 0; p < 4; ++p) {
            const int f = p * 512 + t;          // f4 index
            wst[p] = *(const float4*)&Wp[(size_t)(f >> 3) * D + k0 + (f & 7) * 4];
        }
        if (t < 256) xst = *(const float4*)&x[(size_t)(tok0 + (t >> 3)) * D + k0 + (t & 7) * 4];
    };
    ISSUE(0);

    const float* wbase = &smem[WP_OFF + (hb * 128 + tx) * LDW + ku * 4];
    const float* xbase = &smem[X_OFF + (tb * 8) * LDW + ku * 4];

    for (int c = 0; c < NCH; ++c) {
        __syncthreads();                     // prior chunk's LDS reads done
        #pragma unroll
        for (int p = 0; p < 4; ++p) {
            const int f = p * 512 + t;
            *(float4*)&smem[WP_OFF + (f >> 3) * LDW + (f & 7) * 4] = wst[p];
        }
        if (t < 256) *(float4*)&smem[X_OFF + (t >> 3) * LDW + (t & 7) * 4] = xst;
        __syncthreads();
        if (c + 1 < NCH) ISSUE((c + 1) * BK);   // prefetch under compute

        #pragma unroll
        for (int half = 0; half < 2; ++half) {  // two 16-k passes
            const int co = half * 16;
            float4 xa[8];
            #pragma unroll
            for (int i = 0; i < 8; ++i)
                xa[i] = *(const float4*)&xbase[i * LDW + co];   // broadcast reads
            #pragma unroll
            for (int j = 0; j < 8; ++j) {
                const float4 wvv = *(const float4*)&wbase[j * 16 * LDW + co];
                #pragma unroll
                for (int i = 0; i < 8; ++i) {
                    acc[i][j] = fmaf(xa[i].x, wvv.x, acc[i][j]);
                    acc[i][j] = fmaf(xa[i].y, wvv.y, acc[i][j]);
                    acc[i][j] = fmaf(xa[i].z, wvv.z, acc[i][j]);
                    acc[i][j] = fmaf(xa[i].w, wvv.w, acc[i][j]);
                }
            }
        }
    }

    // ---- k-window reduction: in-wave butterflies over lane bits 4,5 ----
    #pragma unroll
    for (int i = 0; i < 8; ++i)
        #pragma unroll
        for (int j = 0; j < 8; ++j) {
            acc[i][j] += __shfl_xor(acc[i][j], 16);
            acc[i][j] += __shfl_xor(acc[i][j], 32);
        }

    __syncthreads();                          // staging region now dead

    // ---- dump proj into SB [32][257]; stage Wg; zero reducers ----
    if (ku == 0) {
        #pragma unroll
        for (int i = 0; i < 8; ++i)
            #pragma unroll
            for (int j = 0; j < 8; ++j)
                smem[SB_OFF + (tb * 8 + i) * SB_LDW + hb * 128 + tx + 16 * j] = acc[i][j];
    }
    {
        const int fi = t * 8;                 // 512 thr x 8 floats = 4096
        *(float4*)&smem[WG_OFF + fi]     = *(const float4*)&Wg[fi];
        *(float4*)&smem[WG_OFF + fi + 4] = *(const float4*)&Wg[fi + 4];
    }
    if (t < 16)  smem[LB_OFF + t] = 0.f;
    if (t == 16) smem[Z_OFF] = 0.f;
    __syncthreads();

    // ---- post phase: one token per 16-thread slot ----
    const int ptx  = t & 15;
    const int tokl = t >> 4;                  // 0..31
    const int tok  = tok0 + tokl;
    const float temp = fabsf(temp_g[0]) + 1e-6f;

    float lnw[16], lnb[16];
    #pragma unroll
    for (int j = 0; j < 16; ++j) {
        lnw[j] = lnw_g[ptx + 16 * j];
        lnb[j] = lnb_g[ptx + 16 * j];
    }

    float pr[16];
    #pragma unroll
    for (int j = 0; j < 16; ++j)
        pr[j] = smem[SB_OFF + tokl * SB_LDW + ptx + 16 * j];

    // mean / variance over H (16-lane butterfly)
    float s = 0.f;
    #pragma unroll
    for (int j = 0; j < 16; ++j) s += pr[j];
    s += __shfl_xor(s, 1); s += __shfl_xor(s, 2);
    s += __shfl_xor(s, 4); s += __shfl_xor(s, 8);
    const float mu = s * (1.f / 256.f);
    float v = 0.f;
    #pragma unroll
    for (int j = 0; j < 16; ++j) { const float d = pr[j] - mu; v = fmaf(d, d, v); }
    v += __shfl_xor(v, 1); v += __shfl_xor(v, 2);
    v += __shfl_xor(v, 4); v += __shfl_xor(v, 8);
    const float rstd = 1.0f / sqrtf(v * (1.f / 256.f) + 1e-5f);

    float n[16];
    #pragma unroll
    for (int j = 0; j < 16; ++j)
        n[j] = fmaf((pr[j] - mu) * rstd, lnw[j], lnb[j]);

    float p[16];
    #pragma unroll
    for (int e = 0; e < 16; ++e) p[e] = 0.f;
    #pragma unroll
    for (int j = 0; j < 16; ++j) {
        const float nv = n[j];
        const int  h   = ptx + 16 * j;
        #pragma unroll
        for (int e = 0; e < 16; ++e)
            p[e] = fmaf(nv, smem[WG_OFF + e * H + h], p[e]);
    }
    #pragma unroll
    for (int m = 1; m < 16; m <<= 1)
        #pragma unroll
        for (int e = 0; e < 16; ++e) p[e] += __shfl_xor(p[e], m);
    #pragma unroll
    for (int e = 0; e < 16; ++e) p[e] = p[e] / temp;

    float myz = 0.f;
    if (ptx == 0) {
        #pragma unroll
        for (int e = 0; e < 16; ++e) myz = fmaf(p[e], p[e], myz);
    }

    // softmax (stable)
    float mx = p[0];
    #pragma unroll
    for (int e = 1; e < 16; ++e) mx = fmaxf(mx, p[e]);
    float w[16]; float sw = 0.f;
    #pragma unroll
    for (int e = 0; e < 16; ++e) { w[e] = expf(p[e] - mx); sw += w[e]; }
    #pragma unroll
    for (int e = 0; e < 16; ++e) w[e] = w[e] / sw;

    // top-2 (ties -> lower index)
    float w1 = -1.f; int i1 = 0; float w2 = -1.f; int i2 = 0;
    #pragma unroll
    for (int e = 0; e < 16; ++e) {
        const float we = w[e];
        if (we > w1)      { w2 = w1; i2 = i1; w1 = we; i1 = e; }
        else if (we > w2) { w2 = we; i2 = e; }
    }
    const float rs = 1.f / (w1 + w2 + 1e-6f);
    out_rw  [(size_t)tok * E + ptx] = w[ptx];
    out_disp[(size_t)tok * E + ptx] = (ptx == i1) ? w1 * rs : (ptx == i2 ? w2 * rs : 0.f);

    // ---- loss partials ----
    float mylb = w[ptx];
    mylb += __shfl_xor(mylb, 16); mylb += __shfl_xor(mylb, 32);
    myz  += __shfl_xor(myz, 16);  myz  += __shfl_xor(myz, 32);
    if ((t & 63) < 16) atomicAdd(&smem[LB_OFF + ptx], mylb);
    if ((t & 63) == 0) atomicAdd(&smem[Z_OFF], myz);
    __syncthreads();
    if (t < 16)  ws_part[blockIdx.x * WS_STRIDE + t]  = smem[LB_OFF + t];
    if (t == 16) ws_part[blockIdx.x * WS_STRIDE + 16] = smem[Z_OFF];
}

__global__ void router_final(const float* __restrict__ ws_part,
                             float* __restrict__ out_loss, int nblocks, int T)
{
    const int l = threadIdx.x;   // 64 threads
    float lb[16]; float z = 0.f;
    #pragma unroll
    for (int e = 0; e < 16; ++e) lb[e] = 0.f;
    for (int b = l; b < nblocks; b += 64) {
        #pragma unroll
        for (int e = 0; e < 16; ++e) lb[e] += ws_part[b * WS_STRIDE + e];
        z += ws_part[b * WS_STRIDE + 16];
    }
    #pragma unroll
    for (int m = 1; m < 64; m <<= 1) {
        #pragma unroll
        for (int e = 0; e < 16; ++e) lb[e] += __shfl_xor(lb[e], m);
        z += __shfl_xor(z, m);
    }
    if (l == 0) {
        const float zloss = z / (float)(T * 16);
        const float ideal = 1.f / 16.f;
        float lbl = 0.f;
        #pragma unroll
        for (int e = 0; e < 16; ++e) {
            const float a = lb[e] / (float)T;
            lbl += ideal * (logf(ideal) - logf(a));
        }
        lbl *= (1.f / 16.f);
        out_loss[0] = 0.005f * zloss + 0.005f * lbl;
    }
}

extern "C" void kernel_launch(void* const* d_in, const int* in_sizes, int n_in,
                              void* d_out, int out_size, void* d_ws, size_t ws_size,
                              hipStream_t stream)
{
    const float* x    = (const float*)d_in[0];
    const float* Wp   = (const float*)d_in[1];
    const float* Wg   = (const float*)d_in[2];
    const float* lnw  = (const float*)d_in[3];
    const float* lnb  = (const float*)d_in[4];
    const float* temp = (const float*)d_in[5];
    const int T = in_sizes[0] / D;           // 16384
    float* out      = (float*)d_out;
    float* out_rw   = out;
    float* out_disp = out + (size_t)T * E;
    float* out_loss = out + (size_t)2 * T * E;
    float* ws_part  = (float*)d_ws;
    const int nblocks = T / TMB;             // 512

    hipLaunchKernelGGL(router_main, dim3(nblocks), dim3(THREADS), 0, stream,
                       x, Wp, Wg, lnw, lnb, temp, out_rw, out_disp, ws_part);
    hipLaunchKernelGGL(router_final, dim3(1), dim3(64), 0, stream,
                       ws_part, out_loss, nblocks, T);
}

// Round 16
// 299.885 us; speedup vs baseline: 1.5265x; 1.5265x over previous
//
#include <hip/hip_runtime.h>
#include <hip/hip_bf16.h>
#include <math.h>

#define D 2048
#define H 256
#define E 16
#define TMB 32                 // tokens per block
#define BK 16                  // k-chunk; each ku-lane owns a 4-k window
#define NCH (D / BK)           // 128
#define LDK 20                 // Wp LDS row stride (floats): (5*tx+ku)&7 uniform banks
#define LDXK 16                // x LDS row stride
#define WP_OFF 0               // [256][20] = 5120 floats
#define X_OFF  5120            // [32][16]  = 512   (staging ends 5632)
#define SB_LDW 260
#define SB_OFF 0               // post proj buffer [32][260] = 8320 (aliases staging)
#define WG_OFF 8320            // [16][256] = 4096
#define LB_OFF 12416
#define Z_OFF  12432
#define SMEM_FLOATS 12448      // 49.8 KB/block
#define THREADS 512
#define WS_STRIDE 20

// HARD-WON (R5,R8-R15): bare __launch_bounds__(N) ONLY — any occupancy hint
// (2nd arg / waves_per_eu) => 64-VGPR cap or LDS padding => spill. R7 structure
// (this file minus the barrier idiom) measured 345us, VGPR 80, no spill.
__global__ __launch_bounds__(THREADS)
void router_main(const float* __restrict__ x, const float* __restrict__ Wp,
                 const float* __restrict__ Wg, const float* __restrict__ lnw_g,
                 const float* __restrict__ lnb_g, const float* __restrict__ temp_g,
                 float* __restrict__ out_rw, float* __restrict__ out_disp,
                 float* __restrict__ ws_part)
{
    __shared__ __align__(16) float smem[SMEM_FLOATS];
    const int t  = threadIdx.x;
    const int tx = t & 15;           // h-lane (lane bits 0-3)
    const int ku = (t >> 4) & 3;     // private 4-k window (lane bits 4-5)
    const int tb = (t >> 6) & 3;     // token octet (wave bits)
    const int hb = t >> 8;           // h-half (wave bit)
    const int tok0 = blockIdx.x * TMB;

    float acc[8][8];
    #pragma unroll
    for (int i = 0; i < 8; ++i)
        #pragma unroll
        for (int j = 0; j < 8; ++j) acc[i][j] = 0.f;

    // staging registers (transient): Wp 8 floats/thread, x 1 f4 for t<128
    const int wrow = t >> 1;              // 0..255
    const int wcol = (t & 1) * 8;         // 0 or 8
    const int xrw  = t >> 2;              // 0..127
    const int xcl  = (t & 3) * 4;
    float4 wpr0, wpr1, xr;
    auto ISSUE = [&](int k0) {
        wpr0 = *(const float4*)&Wp[(size_t)wrow * D + k0 + wcol];
        wpr1 = *(const float4*)&Wp[(size_t)wrow * D + k0 + wcol + 4];
        if (t < 128) xr = *(const float4*)&x[(size_t)(tok0 + xrw) * D + k0 + xcl];
    };
    ISSUE(0);

    const float* wbase = &smem[WP_OFF + (hb * 128 + tx) * LDK + ku * 4];
    const float* xbase = &smem[X_OFF + (tb * 8) * LDXK + ku * 4];

    for (int c = 0; c < NCH; ++c) {
        // barrier1: prior chunk's LDS reads done. ONLY lgkmcnt — the in-flight
        // ISSUE() global loads (x is HBM, ~900cy) must NOT be drained here
        // (T4 idiom; __syncthreads would emit vmcnt(0) and serialize them).
        asm volatile("s_waitcnt lgkmcnt(0)" ::: "memory");
        __builtin_amdgcn_s_barrier();
        // WRITE: compiler inserts its own counted vmcnt before first wst use.
        *(float4*)&smem[WP_OFF + wrow * LDK + wcol]     = wpr0;
        *(float4*)&smem[WP_OFF + wrow * LDK + wcol + 4] = wpr1;
        if (t < 128) *(float4*)&smem[X_OFF + xrw * LDXK + xcl] = xr;
        // barrier2: writes visible to all waves.
        asm volatile("s_waitcnt lgkmcnt(0)" ::: "memory");
        __builtin_amdgcn_s_barrier();
        if (c + 1 < NCH) ISSUE((c + 1) * BK);   // prefetch: stays in flight

        float4 xa[8];
        #pragma unroll
        for (int i = 0; i < 8; ++i)
            xa[i] = *(const float4*)&xbase[i * LDXK];    // 16-way broadcast reads
        #pragma unroll
        for (int j = 0; j < 8; ++j) {
            const float4 wv = *(const float4*)&wbase[j * 16 * LDK];  // 64-distinct b128
            #pragma unroll
            for (int i = 0; i < 8; ++i) {
                acc[i][j] = fmaf(xa[i].x, wv.x, acc[i][j]);
                acc[i][j] = fmaf(xa[i].y, wv.y, acc[i][j]);
                acc[i][j] = fmaf(xa[i].z, wv.z, acc[i][j]);
                acc[i][j] = fmaf(xa[i].w, wv.w, acc[i][j]);
            }
        }
    }

    // ---- k-window reduction: in-wave butterflies over lane bits 4,5 ----
    #pragma unroll
    for (int i = 0; i < 8; ++i)
        #pragma unroll
        for (int j = 0; j < 8; ++j) {
            acc[i][j] += __shfl_xor(acc[i][j], 16);
            acc[i][j] += __shfl_xor(acc[i][j], 32);
        }

    __syncthreads();                          // staging region now dead (full drain ok, once)

    // ---- dump proj to LDS [32][260]; stage Wg; zero reducers ----
    if (ku == 0) {
        #pragma unroll
        for (int i = 0; i < 8; ++i)
            #pragma unroll
            for (int j = 0; j < 8; ++j)
                smem[SB_OFF + (tb * 8 + i) * SB_LDW + hb * 128 + tx + 16 * j] = acc[i][j];
    }
    {
        const int fi = t * 8;                 // 512 thr x 8 floats = 4096
        *(float4*)&smem[WG_OFF + fi]     = *(const float4*)&Wg[fi];
        *(float4*)&smem[WG_OFF + fi + 4] = *(const float4*)&Wg[fi + 4];
    }
    if (t < 16)  smem[LB_OFF + t] = 0.f;
    if (t == 16) smem[Z_OFF] = 0.f;
    __syncthreads();

    // ---- post phase: one token per (tx, tokl) slot ----
    const int ptx  = t & 15;
    const int tokl = t >> 4;                  // 0..31
    const int tok  = tok0 + tokl;

    float pr[16];
    #pragma unroll
    for (int j = 0; j < 16; ++j)
        pr[j] = smem[SB_OFF + tokl * SB_LDW + ptx + 16 * j];

    float lnw[16], lnb[16];
    #pragma unroll
    for (int j = 0; j < 16; ++j) {
        lnw[j] = lnw_g[ptx + 16 * j];
        lnb[j] = lnb_g[ptx + 16 * j];
    }
    const float temp = fabsf(temp_g[0]) + 1e-6f;

    // mean / variance over H (16-lane butterfly)
    float s = 0.f;
    #pragma unroll
    for (int j = 0; j < 16; ++j) s += pr[j];
    s += __shfl_xor(s, 1); s += __shfl_xor(s, 2);
    s += __shfl_xor(s, 4); s += __shfl_xor(s, 8);
    const float mu = s * (1.f / 256.f);
    float v = 0.f;
    #pragma unroll
    for (int j = 0; j < 16; ++j) { const float d = pr[j] - mu; v = fmaf(d, d, v); }
    v += __shfl_xor(v, 1); v += __shfl_xor(v, 2);
    v += __shfl_xor(v, 4); v += __shfl_xor(v, 8);
    const float rstd = 1.0f / sqrtf(v * (1.f / 256.f) + 1e-5f);

    float n[16];
    #pragma unroll
    for (int j = 0; j < 16; ++j)
        n[j] = fmaf((pr[j] - mu) * rstd, lnw[j], lnb[j]);

    float p[16];
    #pragma unroll
    for (int e = 0; e < 16; ++e) p[e] = 0.f;
    #pragma unroll
    for (int j = 0; j < 16; ++j) {
        const float nv = n[j];
        const int  h   = ptx + 16 * j;
        #pragma unroll
        for (int e = 0; e < 16; ++e)
            p[e] = fmaf(nv, smem[WG_OFF + e * H + h], p[e]);
    }
    #pragma unroll
    for (int m = 1; m < 16; m <<= 1)
        #pragma unroll
        for (int e = 0; e < 16; ++e) p[e] += __shfl_xor(p[e], m);
    #pragma unroll
    for (int e = 0; e < 16; ++e) p[e] = p[e] / temp;

    float myz = 0.f;
    if (ptx == 0) {
        #pragma unroll
        for (int e = 0; e < 16; ++e) myz = fmaf(p[e], p[e], myz);
    }

    // softmax (stable)
    float mx = p[0];
    #pragma unroll
    for (int e = 1; e < 16; ++e) mx = fmaxf(mx, p[e]);
    float w[16]; float sw = 0.f;
    #pragma unroll
    for (int e = 0; e < 16; ++e) { w[e] = expf(p[e] - mx); sw += w[e]; }
    #pragma unroll
    for (int e = 0; e < 16; ++e) w[e] = w[e] / sw;

    // top-2 (ties -> lower index)
    float w1 = -1.f; int i1 = 0; float w2 = -1.f; int i2 = 0;
    #pragma unroll
    for (int e = 0; e < 16; ++e) {
        const float we = w[e];
        if (we > w1)      { w2 = w1; i2 = i1; w1 = we; i1 = e; }
        else if (we > w2) { w2 = we; i2 = e; }
    }
    const float rs = 1.f / (w1 + w2 + 1e-6f);
    out_rw  [(size_t)tok * E + ptx] = w[ptx];
    out_disp[(size_t)tok * E + ptx] = (ptx == i1) ? w1 * rs : (ptx == i2 ? w2 * rs : 0.f);

    // ---- loss partials ----
    float mylb = w[ptx];
    mylb += __shfl_xor(mylb, 16); mylb += __shfl_xor(mylb, 32);
    myz  += __shfl_xor(myz, 16);  myz  += __shfl_xor(myz, 32);
    if ((t & 63) < 16) atomicAdd(&smem[LB_OFF + ptx], mylb);
    if ((t & 63) == 0) atomicAdd(&smem[Z_OFF], myz);
    __syncthreads();
    if (t < 16)  ws_part[blockIdx.x * WS_STRIDE + t]  = smem[LB_OFF + t];
    if (t == 16) ws_part[blockIdx.x * WS_STRIDE + 16] = smem[Z_OFF];
}

__global__ void router_final(const float* __restrict__ ws_part,
                             float* __restrict__ out_loss, int nblocks, int T)
{
    const int l = threadIdx.x;   // 64 threads
    float lb[16]; float z = 0.f;
    #pragma unroll
    for (int e = 0; e < 16; ++e) lb[e] = 0.f;
    for (int b = l; b < nblocks; b += 64) {
        #pragma unroll
        for (int e = 0; e < 16; ++e) lb[e] += ws_part[b * WS_STRIDE + e];
        z += ws_part[b * WS_STRIDE + 16];
    }
    #pragma unroll
    for (int m = 1; m < 64; m <<= 1) {
        #pragma unroll
        for (int e = 0; e < 16; ++e) lb[e] += __shfl_xor(lb[e], m);
        z += __shfl_xor(z, m);
    }
    if (l == 0) {
        const float zloss = z / (float)(T * 16);
        const float ideal = 1.f / 16.f;
        float lbl = 0.f;
        #pragma unroll
        for (int e = 0; e < 16; ++e) {
            const float a = lb[e] / (float)T;
            lbl += ideal * (logf(ideal) - logf(a));
        }
        lbl *= (1.f / 16.f);
        out_loss[0] = 0.005f * zloss + 0.005f * lbl;
    }
}

extern "C" void kernel_launch(void* const* d_in, const int* in_sizes, int n_in,
                              void* d_out, int out_size, void* d_ws, size_t ws_size,
                              hipStream_t stream)
{
    const float* x    = (const float*)d_in[0];
    const float* Wp   = (const float*)d_in[1];
    const float* Wg   = (const float*)d_in[2];
    const float* lnw  = (const float*)d_in[3];
    const float* lnb  = (const float*)d_in[4];
    const float* temp = (const float*)d_in[5];
    const int T = in_sizes[0] / D;           // 16384
    float* out      = (float*)d_out;
    float* out_rw   = out;
    float* out_disp = out + (size_t)T * E;
    float* out_loss = out + (size_t)2 * T * E;
    float* ws_part  = (float*)d_ws;
    const int nblocks = T / TMB;             // 512

    hipLaunchKernelGGL(router_main, dim3(nblocks), dim3(THREADS), 0, stream,
                       x, Wp, Wg, lnw, lnb, temp, out_rw, out_disp, ws_part);
    hipLaunchKernelGGL(router_final, dim3(1), dim3(64), 0, stream,
                       ws_part, out_loss, nblocks, T);
}